// Round 1
// baseline (321.821 us; speedup 1.0000x reference)
//
#include <hip/hip_runtime.h>
#include <cstddef>

// ---------------------------------------------------------------------------
// GCN forward: 3 x ( h@W -> gather/segment_sum over CSR -> LayerNorm -> ReLU? )
// N=50000 nodes, E=800000 edges, D: 128 -> 128 -> 128 -> 64
// ---------------------------------------------------------------------------

#define BM 64
#define BN 64
#define BK 32

// Tiled fp32 GEMM: C[M,N] = A[M,K] @ B[K,N].  K,N multiples of {32,64}; M guarded.
__global__ __launch_bounds__(256) void sgemm_kernel(const float* __restrict__ A,
                                                    const float* __restrict__ B,
                                                    float* __restrict__ C,
                                                    int M, int N, int K) {
    __shared__ float As[BK][BM];   // transposed A tile: As[k][m]
    __shared__ float Bs[BK][BN];   // Bs[k][n]

    const int tid = threadIdx.x;
    const int tx = tid & 15;   // col group 0..15
    const int ty = tid >> 4;   // row group 0..15
    const int rowBase = blockIdx.x * BM;
    const int colBase = blockIdx.y * BN;

    float acc[4][4] = {};

    for (int k0 = 0; k0 < K; k0 += BK) {
        // Load A tile: 64 rows x 32 k = 2048 floats -> 2 float4 per thread.
        #pragma unroll
        for (int i = 0; i < 2; ++i) {
            int idx = tid + i * 256;        // 0..511
            int r   = idx >> 3;             // 0..63
            int c   = idx & 7;              // float4 group over k, 0..7
            int grow = rowBase + r;
            float4 v = make_float4(0.f, 0.f, 0.f, 0.f);
            if (grow < M)
                v = *(const float4*)(A + (size_t)grow * K + k0 + c * 4);
            As[c * 4 + 0][r] = v.x;
            As[c * 4 + 1][r] = v.y;
            As[c * 4 + 2][r] = v.z;
            As[c * 4 + 3][r] = v.w;
        }
        // Load B tile: 32 k x 64 n -> 2 float4 per thread.
        #pragma unroll
        for (int i = 0; i < 2; ++i) {
            int idx = tid + i * 256;
            int k   = idx >> 4;             // 0..31
            int n4  = idx & 15;             // 0..15
            float4 v = *(const float4*)(B + (size_t)(k0 + k) * N + colBase + n4 * 4);
            *(float4*)&Bs[k][n4 * 4] = v;
        }
        __syncthreads();

        #pragma unroll
        for (int kk = 0; kk < BK; ++kk) {
            float4 a = *(const float4*)&As[kk][ty * 4];
            float4 b = *(const float4*)&Bs[kk][tx * 4];
            float am[4] = {a.x, a.y, a.z, a.w};
            float bn[4] = {b.x, b.y, b.z, b.w};
            #pragma unroll
            for (int i = 0; i < 4; ++i)
                #pragma unroll
                for (int j = 0; j < 4; ++j)
                    acc[i][j] += am[i] * bn[j];
        }
        __syncthreads();
    }

    #pragma unroll
    for (int i = 0; i < 4; ++i) {
        int row = rowBase + ty * 4 + i;
        if (row < M) {
            float4 v = make_float4(acc[i][0], acc[i][1], acc[i][2], acc[i][3]);
            *(float4*)(C + (size_t)row * N + colBase + tx * 4) = v;
        }
    }
}

// Fused CSR segment-sum + LayerNorm (+ optional ReLU).
// One 64-lane wave per node; each lane owns D/64 consecutive features.
template <int D, bool RELU>
__global__ __launch_bounds__(64) void agg_ln_kernel(const float* __restrict__ xw,
                                                    const int* __restrict__ ptr,
                                                    const int* __restrict__ col,
                                                    float* __restrict__ out) {
    constexpr int V = D / 64;   // 2 for D=128, 1 for D=64
    const int node = blockIdx.x;
    const int lane = threadIdx.x;
    const int s = ptr[node];
    const int e = ptr[node + 1];

    float acc[V];
    #pragma unroll
    for (int v = 0; v < V; ++v) acc[v] = 0.f;

    for (int i = s; i < e; ++i) {
        const int src = col[i];
        const float* row = xw + (size_t)src * D + lane * V;
        if constexpr (V == 2) {
            float2 v = *(const float2*)row;
            acc[0] += v.x;
            acc[1] += v.y;
        } else {
            acc[0] += row[0];
        }
    }

    // LayerNorm across the D features (one wave -> shuffle butterfly).
    float s1 = 0.f, s2 = 0.f;
    #pragma unroll
    for (int v = 0; v < V; ++v) { s1 += acc[v]; s2 += acc[v] * acc[v]; }
    #pragma unroll
    for (int m = 32; m >= 1; m >>= 1) {
        s1 += __shfl_xor(s1, m, 64);
        s2 += __shfl_xor(s2, m, 64);
    }
    const float mean = s1 / (float)D;
    const float var  = s2 / (float)D - mean * mean;
    const float inv  = rsqrtf(var + 1e-5f);

    float* orow = out + (size_t)node * D + lane * V;
    if constexpr (V == 2) {
        float2 o;
        o.x = (acc[0] - mean) * inv;
        o.y = (acc[1] - mean) * inv;
        if (RELU) { o.x = fmaxf(o.x, 0.f); o.y = fmaxf(o.y, 0.f); }
        *(float2*)orow = o;
    } else {
        float x = (acc[0] - mean) * inv;
        if (RELU) x = fmaxf(x, 0.f);
        orow[0] = x;
    }
}

extern "C" void kernel_launch(void* const* d_in, const int* in_sizes, int n_in,
                              void* d_out, int out_size, void* d_ws, size_t ws_size,
                              hipStream_t stream) {
    const float* feat = (const float*)d_in[0];   // [N,128]
    const float* W0   = (const float*)d_in[1];   // [128,128]
    const float* W1   = (const float*)d_in[2];   // [128,128]
    const float* W2   = (const float*)d_in[3];   // [128,64]
    const int*   ptr  = (const int*)d_in[4];     // [N+1]
    const int*   col  = (const int*)d_in[5];     // [E] source indices
    // d_in[6] = edge_rows, unused (CSR ptr encodes the same segments)

    const int N = in_sizes[4] - 1;               // 50000

    float* buf0 = (float*)d_ws;                  // [N,128] scratch (xw)
    float* buf1 = buf0 + (size_t)N * 128;        // [N,128] scratch (h)
    float* out  = (float*)d_out;                 // [N,64]

    const int rowTiles = (N + BM - 1) / BM;      // 782

    // Layer 0: xw = feat @ W0 ; h = relu(LN(A @ xw))
    sgemm_kernel<<<dim3(rowTiles, 128 / BN), 256, 0, stream>>>(feat, W0, buf0, N, 128, 128);
    agg_ln_kernel<128, true><<<N, 64, 0, stream>>>(buf0, ptr, col, buf1);

    // Layer 1
    sgemm_kernel<<<dim3(rowTiles, 128 / BN), 256, 0, stream>>>(buf1, W1, buf0, N, 128, 128);
    agg_ln_kernel<128, true><<<N, 64, 0, stream>>>(buf0, ptr, col, buf1);

    // Layer 2 (D_out = 64, no ReLU)
    sgemm_kernel<<<dim3(rowTiles, 64 / BN), 256, 0, stream>>>(buf1, W2, buf0, N, 64, 128);
    agg_ln_kernel<64, false><<<N, 64, 0, stream>>>(buf0, ptr, col, out);
}

// Round 4
// 303.867 us; speedup vs baseline: 1.0591x; 1.0591x over previous
//
#include <hip/hip_runtime.h>
#include <cstddef>

// ---------------------------------------------------------------------------
// GCN forward: 3 x ( h@W fp32 sgemm -> packed-bf16 xw -> CSR segsum+LN(+ReLU) )
// N=50000, E=800000, D: 128 -> 128 -> 128 -> 64.
// The xw gather table is unsigned int (two packed bf16 per element) with NO
// pointer-type casts anywhere: GEMM stores uint, agg loads uint. R2/R3 failed
// with an all-zero-output signature and the only shared construct was
// uint-from-ushort* type-punned access; this round eliminates it.
// ---------------------------------------------------------------------------

#define BM 64
#define BN 64
#define BK 32

static __device__ __forceinline__ unsigned int f2bf(float f) {
    // round-to-nearest-even f32 -> bf16, returned in low 16 bits
    union { float f; unsigned int u; } v; v.f = f;
    unsigned int u = v.u;
    u += 0x7fffu + ((u >> 16) & 1u);
    return u >> 16;
}
static __device__ __forceinline__ float bf_lo(unsigned int p) {
    union { unsigned int u; float f; } v; v.u = p << 16; return v.f;
}
static __device__ __forceinline__ float bf_hi(unsigned int p) {
    union { unsigned int u; float f; } v; v.u = p & 0xffff0000u; return v.f;
}

// Tiled fp32 GEMM: C[M,NF] = A[M,K] @ B[K,NF]; C stored as uint-packed bf16
// pairs, row stride NF/2 uints. Identical to round-1's passing sgemm except
// the epilogue.
__global__ __launch_bounds__(256) void sgemm_pack(const float* __restrict__ A,
                                                  const float* __restrict__ B,
                                                  unsigned int* __restrict__ C,
                                                  int M, int NF, int K) {
    __shared__ float As[BK][BM];   // transposed A tile: As[k][m]
    __shared__ float Bs[BK][BN];   // Bs[k][n]

    const int tid = threadIdx.x;
    const int tx = tid & 15;   // col group 0..15
    const int ty = tid >> 4;   // row group 0..15
    const int rowBase = blockIdx.x * BM;
    const int colBase = blockIdx.y * BN;

    float acc[4][4] = {};

    for (int k0 = 0; k0 < K; k0 += BK) {
        #pragma unroll
        for (int i = 0; i < 2; ++i) {
            int idx = tid + i * 256;        // 0..511
            int r   = idx >> 3;             // 0..63
            int c   = idx & 7;              // float4 group over k
            int grow = rowBase + r;
            float4 v = make_float4(0.f, 0.f, 0.f, 0.f);
            if (grow < M)
                v = *(const float4*)(A + (size_t)grow * K + k0 + c * 4);
            As[c * 4 + 0][r] = v.x;
            As[c * 4 + 1][r] = v.y;
            As[c * 4 + 2][r] = v.z;
            As[c * 4 + 3][r] = v.w;
        }
        #pragma unroll
        for (int i = 0; i < 2; ++i) {
            int idx = tid + i * 256;
            int k   = idx >> 4;             // 0..31
            int n4  = idx & 15;             // 0..15
            float4 v = *(const float4*)(B + (size_t)(k0 + k) * NF + colBase + n4 * 4);
            *(float4*)&Bs[k][n4 * 4] = v;
        }
        __syncthreads();

        #pragma unroll
        for (int kk = 0; kk < BK; ++kk) {
            float4 a = *(const float4*)&As[kk][ty * 4];
            float4 b = *(const float4*)&Bs[kk][tx * 4];
            float am[4] = {a.x, a.y, a.z, a.w};
            float bn[4] = {b.x, b.y, b.z, b.w};
            #pragma unroll
            for (int i = 0; i < 4; ++i)
                #pragma unroll
                for (int j = 0; j < 4; ++j)
                    acc[i][j] += am[i] * bn[j];
        }
        __syncthreads();
    }

    const int rowStride = NF >> 1;                 // uints per row
    #pragma unroll
    for (int i = 0; i < 4; ++i) {
        int row = rowBase + ty * 4 + i;
        if (row < M) {
            unsigned int p0 = (f2bf(acc[i][1]) << 16) | f2bf(acc[i][0]);
            unsigned int p1 = (f2bf(acc[i][3]) << 16) | f2bf(acc[i][2]);
            size_t base = (size_t)row * rowStride + (colBase >> 1) + tx * 2;
            C[base]     = p0;
            C[base + 1] = p1;
        }
    }
}

// Fused CSR segment-sum (packed-bf16 gather) + LayerNorm (+ReLU), fp32 math.
// One 64-lane wave per node (round-1 proven config). xw rows: D/2 uints.
template <int D, bool RELU>
__global__ __launch_bounds__(64) void agg_ln_kernel(const unsigned int* __restrict__ xw,
                                                    const int* __restrict__ ptr,
                                                    const int* __restrict__ col,
                                                    float* __restrict__ out) {
    const int node = blockIdx.x;
    const int lane = threadIdx.x;
    const int s = ptr[node];
    const int e = ptr[node + 1];

    float a0 = 0.f, a1 = 0.f;

    if constexpr (D == 128) {
        // lane owns features {2*lane, 2*lane+1}: one uint load per edge
        for (int i = s; i < e; ++i) {
            const int src = col[i];
            unsigned int v = xw[(size_t)src * 64 + lane];
            a0 += bf_lo(v);
            a1 += bf_hi(v);
        }
    } else {
        // D == 64: row = 32 uints; lane pair shares a uint (coalesced, 2-way bcast)
        for (int i = s; i < e; ++i) {
            unsigned int v = xw[(size_t)col[i] * 32 + (lane >> 1)];
            a0 += (lane & 1) ? bf_hi(v) : bf_lo(v);
        }
    }

    // LayerNorm across D features (wave shuffle butterfly).
    float s1 = a0 + a1;
    float s2 = a0 * a0 + a1 * a1;
    #pragma unroll
    for (int m = 32; m >= 1; m >>= 1) {
        s1 += __shfl_xor(s1, m, 64);
        s2 += __shfl_xor(s2, m, 64);
    }
    const float mean = s1 / (float)D;
    const float var  = s2 / (float)D - mean * mean;
    const float inv  = rsqrtf(var + 1e-5f);

    float o0 = (a0 - mean) * inv;
    float o1 = (a1 - mean) * inv;
    if (RELU) { o0 = fmaxf(o0, 0.f); o1 = fmaxf(o1, 0.f); }

    if constexpr (D == 128) {
        float2 o; o.x = o0; o.y = o1;
        *((float2*)out + (size_t)node * 64 + lane) = o;
    } else {
        out[(size_t)node * 64 + lane] = o0;
    }
}

extern "C" void kernel_launch(void* const* d_in, const int* in_sizes, int n_in,
                              void* d_out, int out_size, void* d_ws, size_t ws_size,
                              hipStream_t stream) {
    const float* feat = (const float*)d_in[0];   // [N,128]
    const float* W0   = (const float*)d_in[1];   // [128,128]
    const float* W1   = (const float*)d_in[2];   // [128,128]
    const float* W2   = (const float*)d_in[3];   // [128,64]
    const int*   ptr  = (const int*)d_in[4];     // [N+1]
    const int*   col  = (const int*)d_in[5];     // [E]
    // d_in[6] = edge_rows, unused (CSR ptr encodes the same segments)

    const int N = in_sizes[4] - 1;               // 50000

    unsigned int* xwp = (unsigned int*)d_ws;             // [N,64] uint (bf16x2)
    float*        hf  = (float*)(xwp + (size_t)N * 64);  // [N,128] fp32 h
    float*        out = (float*)d_out;                   // [N,64]

    const int rowTiles = (N + BM - 1) / BM;      // 782

    // Layer 0
    sgemm_pack<<<dim3(rowTiles, 128 / BN), 256, 0, stream>>>(feat, W0, xwp, N, 128, 128);
    agg_ln_kernel<128, true><<<N, 64, 0, stream>>>(xwp, ptr, col, hf);
    // Layer 1
    sgemm_pack<<<dim3(rowTiles, 128 / BN), 256, 0, stream>>>(hf, W1, xwp, N, 128, 128);
    agg_ln_kernel<128, true><<<N, 64, 0, stream>>>(xwp, ptr, col, hf);
    // Layer 2 (D_out=64, no ReLU)
    sgemm_pack<<<dim3(rowTiles, 64 / BN), 256, 0, stream>>>(hf, W2, xwp, N, 64, 128);
    agg_ln_kernel<64, false><<<N, 64, 0, stream>>>(xwp, ptr, col, out);
}

// Round 5
// 294.153 us; speedup vs baseline: 1.0941x; 1.0330x over previous
//
#include <hip/hip_runtime.h>
#include <cstddef>

// ---------------------------------------------------------------------------
// GCN forward: 3 x ( h@W bf16 MFMA -> packed-bf16 xw -> CSR segsum+LN(+ReLU) )
// N=50000, E=800000, D: 128 -> 128 -> 128 -> 64.
// R4-proven agg + buffer scheme kept bit-identical; only the GEMM changed
// (fp32 vector sgemm -> mfma_f32_16x16x32_bf16, A converted in-register,
// W pre-transposed to packed-uint bf16 pairs, all stores packed-uint).
// ---------------------------------------------------------------------------

typedef __attribute__((ext_vector_type(8))) short bf16x8;
typedef __attribute__((ext_vector_type(4))) float floatx4;
typedef __attribute__((ext_vector_type(4))) unsigned int uintx4;

static __device__ __forceinline__ unsigned int f2bf(float f) {
    // round-to-nearest-even f32 -> bf16, returned in low 16 bits
    union { float f; unsigned int u; } v; v.f = f;
    unsigned int u = v.u;
    u += 0x7fffu + ((u >> 16) & 1u);
    return u >> 16;
}
static __device__ __forceinline__ float bf_lo(unsigned int p) {
    union { unsigned int u; float f; } v; v.u = p << 16; return v.f;
}
static __device__ __forceinline__ float bf_hi(unsigned int p) {
    union { unsigned int u; float f; } v; v.u = p & 0xffff0000u; return v.f;
}

// ---- W[k][n] fp32 -> Wt[n][kk] packed bf16 pairs (uint), 3 matrices --------
// Slot stride 128*64 uints. Wt[n*64+kk] packs k=2kk (lo) and k=2kk+1 (hi).
__global__ __launch_bounds__(256) void cvt_w(const float* __restrict__ W0,
                                             const float* __restrict__ W1,
                                             const float* __restrict__ W2,
                                             unsigned int* __restrict__ Wt) {
    const int m = blockIdx.x;
    const float* W = (m == 0) ? W0 : (m == 1) ? W1 : W2;
    const int ncols = (m == 2) ? 64 : 128;
    unsigned int* dst = Wt + m * 128 * 64;
    for (int idx = threadIdx.x; idx < ncols * 64; idx += 256) {
        int n = idx >> 6, kk = idx & 63;
        unsigned int lo = f2bf(W[(size_t)(2 * kk) * ncols + n]);
        unsigned int hi = f2bf(W[(size_t)(2 * kk + 1) * ncols + n]);
        dst[idx] = (hi << 16) | lo;
    }
}

// ---- bf16 MFMA GEMM: C[M,NCOLS] = bf16(A[M,128]) @ bf16(W), no LDS --------
// A fp32 row-major (converted in-register); Wt packed-uint transposed
// [NCOLS][64]; C packed-uint bf16 pairs [M][NCOLS/2].
// 4 waves/block; wave computes 16 rows x NCOLS via 16x16x32 MFMA.
template <int NCOLS>
__global__ __launch_bounds__(256) void gemm_mfma(const float* __restrict__ A,
                                                 const unsigned int* __restrict__ Wt,
                                                 unsigned int* __restrict__ C,
                                                 int M) {
    const int lane = threadIdx.x & 63;
    const int wave = threadIdx.x >> 6;
    const int row0 = blockIdx.x * 64 + wave * 16;
    const int quad = lane >> 4;        // k-group: k = quad*8 + j
    const int mcol = lane & 15;        // A row within tile / C col within tile
    const int arow_idx = row0 + mcol;
    const int aload = (arow_idx < M) ? arow_idx : (M - 1);

    constexpr int NT = NCOLS / 16;
    floatx4 acc[NT];
    #pragma unroll
    for (int t = 0; t < NT; ++t) acc[t] = (floatx4){0.f, 0.f, 0.f, 0.f};

    const float* arow = A + (size_t)aload * 128 + quad * 8;

    #pragma unroll
    for (int k0 = 0; k0 < 128; k0 += 32) {
        // A fragment: 8 consecutive fp32 -> bf16x8 (by value, no punning)
        float4 fa = *(const float4*)(arow + k0);
        float4 fb = *(const float4*)(arow + k0 + 4);
        uintx4 ap;
        ap.x = (f2bf(fa.y) << 16) | f2bf(fa.x);
        ap.y = (f2bf(fa.w) << 16) | f2bf(fa.z);
        ap.z = (f2bf(fb.y) << 16) | f2bf(fb.x);
        ap.w = (f2bf(fb.w) << 16) | f2bf(fb.z);
        bf16x8 a = __builtin_bit_cast(bf16x8, ap);

        const int koff = (k0 + quad * 8) >> 1;   // uint offset within Wt row
        #pragma unroll
        for (int t = 0; t < NT; ++t) {
            const unsigned int* brow = Wt + (size_t)(t * 16 + mcol) * 64 + koff;
            uintx4 bp = *(const uintx4*)brow;
            bf16x8 b = __builtin_bit_cast(bf16x8, bp);
            acc[t] = __builtin_amdgcn_mfma_f32_16x16x32_bf16(a, b, acc[t], 0, 0, 0);
        }
    }

    // C/D layout: col = lane&15, row = quad*4 + reg  [m89/m91].
    // Pack adjacent columns (adjacent lanes) into one uint; even lanes store.
    const int rowStride = NCOLS >> 1;  // uints per C row
    #pragma unroll
    for (int t = 0; t < NT; ++t) {
        #pragma unroll
        for (int r = 0; r < 4; ++r) {
            unsigned int mybf = f2bf(acc[t][r]);
            unsigned int pair = __shfl_xor(mybf, 1, 64);   // partner column
            int orow = row0 + quad * 4 + r;
            if (orow < M && (mcol & 1) == 0) {
                unsigned int packed = (pair << 16) | mybf;
                C[(size_t)orow * rowStride + t * 8 + (mcol >> 1)] = packed;
            }
        }
    }
}

// ---- fused CSR segment-sum (packed-bf16 gather) + LayerNorm (+ReLU) --------
// One 64-lane wave per node (R4-proven, unchanged). xw rows: D/2 uints.
template <int D, bool RELU>
__global__ __launch_bounds__(64) void agg_ln_kernel(const unsigned int* __restrict__ xw,
                                                    const int* __restrict__ ptr,
                                                    const int* __restrict__ col,
                                                    float* __restrict__ out) {
    const int node = blockIdx.x;
    const int lane = threadIdx.x;
    const int s = ptr[node];
    const int e = ptr[node + 1];

    float a0 = 0.f, a1 = 0.f;

    if constexpr (D == 128) {
        for (int i = s; i < e; ++i) {
            const int src = col[i];
            unsigned int v = xw[(size_t)src * 64 + lane];
            a0 += bf_lo(v);
            a1 += bf_hi(v);
        }
    } else {
        for (int i = s; i < e; ++i) {
            unsigned int v = xw[(size_t)col[i] * 32 + (lane >> 1)];
            a0 += (lane & 1) ? bf_hi(v) : bf_lo(v);
        }
    }

    float s1 = a0 + a1;
    float s2 = a0 * a0 + a1 * a1;
    #pragma unroll
    for (int m = 32; m >= 1; m >>= 1) {
        s1 += __shfl_xor(s1, m, 64);
        s2 += __shfl_xor(s2, m, 64);
    }
    const float mean = s1 / (float)D;
    const float var  = s2 / (float)D - mean * mean;
    const float inv  = rsqrtf(var + 1e-5f);

    float o0 = (a0 - mean) * inv;
    float o1 = (a1 - mean) * inv;
    if (RELU) { o0 = fmaxf(o0, 0.f); o1 = fmaxf(o1, 0.f); }

    if constexpr (D == 128) {
        float2 o; o.x = o0; o.y = o1;
        *((float2*)out + (size_t)node * 64 + lane) = o;
    } else {
        out[(size_t)node * 64 + lane] = o0;
    }
}

extern "C" void kernel_launch(void* const* d_in, const int* in_sizes, int n_in,
                              void* d_out, int out_size, void* d_ws, size_t ws_size,
                              hipStream_t stream) {
    const float* feat = (const float*)d_in[0];   // [N,128]
    const float* W0   = (const float*)d_in[1];   // [128,128]
    const float* W1   = (const float*)d_in[2];   // [128,128]
    const float* W2   = (const float*)d_in[3];   // [128,64]
    const int*   ptr  = (const int*)d_in[4];     // [N+1]
    const int*   col  = (const int*)d_in[5];     // [E]
    // d_in[6] = edge_rows, unused (CSR ptr encodes the same segments)

    const int N = in_sizes[4] - 1;               // 50000

    unsigned int* xwp = (unsigned int*)d_ws;             // [N,64] uint (bf16x2)
    float*        hf  = (float*)(xwp + (size_t)N * 64);  // [N,128] fp32 h
    unsigned int* WtP = (unsigned int*)(hf + (size_t)N * 128);  // 3 x [128,64] uint
    float*        out = (float*)d_out;                   // [N,64]

    const int gemmBlocks = (N + 63) / 64;        // 782

    cvt_w<<<3, 256, 0, stream>>>(W0, W1, W2, WtP);

    // Layer 0
    gemm_mfma<128><<<gemmBlocks, 256, 0, stream>>>(feat, WtP, xwp, N);
    agg_ln_kernel<128, true><<<N, 64, 0, stream>>>(xwp, ptr, col, hf);
    // Layer 1
    gemm_mfma<128><<<gemmBlocks, 256, 0, stream>>>(hf, WtP + 128 * 64, xwp, N);
    agg_ln_kernel<128, true><<<N, 64, 0, stream>>>(xwp, ptr, col, hf);
    // Layer 2 (D_out=64, no ReLU)
    gemm_mfma<64><<<gemmBlocks, 256, 0, stream>>>(hf, WtP + 2 * 128 * 64, xwp, N);
    agg_ln_kernel<64, false><<<N, 64, 0, stream>>>(xwp, ptr, col, out);
}

// Round 6
// 247.459 us; speedup vs baseline: 1.3005x; 1.1887x over previous
//
#include <hip/hip_runtime.h>
#include <cstddef>

// ---------------------------------------------------------------------------
// GCN forward: 3 x ( h@W bf16 MFMA -> packed-bf16 xw -> CSR segsum+LN(+ReLU) )
// N=50000, E=800000, D: 128 -> 128 -> 128 -> 64.
// R6 change vs R5 (passing): agg restructured 4-edges-in-parallel (16 lanes x
// uintx4 per edge) to fix gather latency-boundedness; cvt_w reads coalesced +
// 48-block grid. MFMA GEMM bit-identical to R5.
// ---------------------------------------------------------------------------

typedef __attribute__((ext_vector_type(8))) short bf16x8;
typedef __attribute__((ext_vector_type(4))) float floatx4;
typedef __attribute__((ext_vector_type(4))) unsigned int uintx4;
typedef __attribute__((ext_vector_type(2))) unsigned int uintx2;

static __device__ __forceinline__ unsigned int f2bf(float f) {
    // round-to-nearest-even f32 -> bf16, returned in low 16 bits
    union { float f; unsigned int u; } v; v.f = f;
    unsigned int u = v.u;
    u += 0x7fffu + ((u >> 16) & 1u);
    return u >> 16;
}
static __device__ __forceinline__ float bf_lo(unsigned int p) {
    union { unsigned int u; float f; } v; v.u = p << 16; return v.f;
}
static __device__ __forceinline__ float bf_hi(unsigned int p) {
    union { unsigned int u; float f; } v; v.u = p & 0xffff0000u; return v.f;
}

// ---- W[k][n] fp32 -> Wt[n][kk] packed bf16 pairs (uint), 3 matrices --------
// Grid: 48 blocks = 3 matrices x 16 slices. Reads coalesced (n fastest).
__global__ __launch_bounds__(256) void cvt_w(const float* __restrict__ W0,
                                             const float* __restrict__ W1,
                                             const float* __restrict__ W2,
                                             unsigned int* __restrict__ Wt) {
    const int m = blockIdx.x >> 4;
    const int slice = blockIdx.x & 15;
    const float* W = (m == 0) ? W0 : (m == 1) ? W1 : W2;
    const int ncols = (m == 2) ? 64 : 128;
    unsigned int* dst = Wt + m * 128 * 64;
    const int total = ncols * 64;
    for (int idx = slice * 256 + threadIdx.x; idx < total; idx += 16 * 256) {
        int kk = idx / ncols;          // 0..63
        int n  = idx - kk * ncols;     // consecutive threads -> consecutive n
        unsigned int lo = f2bf(W[(size_t)(2 * kk) * ncols + n]);
        unsigned int hi = f2bf(W[(size_t)(2 * kk + 1) * ncols + n]);
        dst[(size_t)n * 64 + kk] = (hi << 16) | lo;
    }
}

// ---- bf16 MFMA GEMM: C[M,NCOLS] = bf16(A[M,128]) @ bf16(W), no LDS --------
// (bit-identical to R5's passing kernel)
template <int NCOLS>
__global__ __launch_bounds__(256) void gemm_mfma(const float* __restrict__ A,
                                                 const unsigned int* __restrict__ Wt,
                                                 unsigned int* __restrict__ C,
                                                 int M) {
    const int lane = threadIdx.x & 63;
    const int wave = threadIdx.x >> 6;
    const int row0 = blockIdx.x * 64 + wave * 16;
    const int quad = lane >> 4;
    const int mcol = lane & 15;
    const int arow_idx = row0 + mcol;
    const int aload = (arow_idx < M) ? arow_idx : (M - 1);

    constexpr int NT = NCOLS / 16;
    floatx4 acc[NT];
    #pragma unroll
    for (int t = 0; t < NT; ++t) acc[t] = (floatx4){0.f, 0.f, 0.f, 0.f};

    const float* arow = A + (size_t)aload * 128 + quad * 8;

    #pragma unroll
    for (int k0 = 0; k0 < 128; k0 += 32) {
        float4 fa = *(const float4*)(arow + k0);
        float4 fb = *(const float4*)(arow + k0 + 4);
        uintx4 ap;
        ap.x = (f2bf(fa.y) << 16) | f2bf(fa.x);
        ap.y = (f2bf(fa.w) << 16) | f2bf(fa.z);
        ap.z = (f2bf(fb.y) << 16) | f2bf(fb.x);
        ap.w = (f2bf(fb.w) << 16) | f2bf(fb.z);
        bf16x8 a = __builtin_bit_cast(bf16x8, ap);

        const int koff = (k0 + quad * 8) >> 1;
        #pragma unroll
        for (int t = 0; t < NT; ++t) {
            const unsigned int* brow = Wt + (size_t)(t * 16 + mcol) * 64 + koff;
            uintx4 bp = *(const uintx4*)brow;
            bf16x8 b = __builtin_bit_cast(bf16x8, bp);
            acc[t] = __builtin_amdgcn_mfma_f32_16x16x32_bf16(a, b, acc[t], 0, 0, 0);
        }
    }

    const int rowStride = NCOLS >> 1;
    #pragma unroll
    for (int t = 0; t < NT; ++t) {
        #pragma unroll
        for (int r = 0; r < 4; ++r) {
            unsigned int mybf = f2bf(acc[t][r]);
            unsigned int pair = __shfl_xor(mybf, 1, 64);
            int orow = row0 + quad * 4 + r;
            if (orow < M && (mcol & 1) == 0) {
                unsigned int packed = (pair << 16) | mybf;
                C[(size_t)orow * rowStride + t * 8 + (mcol >> 1)] = packed;
            }
        }
    }
}

// ---- fused CSR segsum + LN (+ReLU), D=128: 4 edges in parallel -------------
// Wave per node; lane = (g, sl): g=edge group (4), sl=feature sub-lane (16).
// Each sl owns 8 features (uintx4 = 16B load). Serial chain ~deg/4.
template <bool RELU>
__global__ __launch_bounds__(256) void agg_ln128(const unsigned int* __restrict__ xw,
                                                 const int* __restrict__ ptr,
                                                 const int* __restrict__ col,
                                                 float* __restrict__ out, int N) {
    const int node = blockIdx.x * 4 + (threadIdx.x >> 6);
    if (node >= N) return;
    const int lane = threadIdx.x & 63;
    const int g  = lane >> 4;
    const int sl = lane & 15;
    const int s = ptr[node];
    const int e = ptr[node + 1];

    float acc[8] = {};
    for (int i = s + g; i < e; i += 4) {
        const int src = col[i];
        uintx4 v = *(const uintx4*)(xw + (size_t)src * 64 + sl * 4);
        acc[0] += bf_lo(v.x); acc[1] += bf_hi(v.x);
        acc[2] += bf_lo(v.y); acc[3] += bf_hi(v.y);
        acc[4] += bf_lo(v.z); acc[5] += bf_hi(v.z);
        acc[6] += bf_lo(v.w); acc[7] += bf_hi(v.w);
    }
    // combine the 4 edge groups (lanes differing in bits 4,5)
    #pragma unroll
    for (int j = 0; j < 8; ++j) {
        acc[j] += __shfl_xor(acc[j], 16, 64);
        acc[j] += __shfl_xor(acc[j], 32, 64);
    }
    // LayerNorm stats across the 16 sub-lanes
    float s1 = 0.f, s2 = 0.f;
    #pragma unroll
    for (int j = 0; j < 8; ++j) { s1 += acc[j]; s2 += acc[j] * acc[j]; }
    #pragma unroll
    for (int m = 8; m >= 1; m >>= 1) {
        s1 += __shfl_xor(s1, m, 64);
        s2 += __shfl_xor(s2, m, 64);
    }
    const float mean = s1 * (1.0f / 128.0f);
    const float var  = s2 * (1.0f / 128.0f) - mean * mean;
    const float inv  = rsqrtf(var + 1e-5f);

    if (g < 2) {
        float4 o;
        o.x = (acc[g * 4 + 0] - mean) * inv;
        o.y = (acc[g * 4 + 1] - mean) * inv;
        o.z = (acc[g * 4 + 2] - mean) * inv;
        o.w = (acc[g * 4 + 3] - mean) * inv;
        if (RELU) {
            o.x = fmaxf(o.x, 0.f); o.y = fmaxf(o.y, 0.f);
            o.z = fmaxf(o.z, 0.f); o.w = fmaxf(o.w, 0.f);
        }
        *(float4*)(out + (size_t)node * 128 + sl * 8 + g * 4) = o;
    }
}

// ---- same, D=64 (uintx2 per edge, 4 features per sub-lane) -----------------
template <bool RELU>
__global__ __launch_bounds__(256) void agg_ln64(const unsigned int* __restrict__ xw,
                                                const int* __restrict__ ptr,
                                                const int* __restrict__ col,
                                                float* __restrict__ out, int N) {
    const int node = blockIdx.x * 4 + (threadIdx.x >> 6);
    if (node >= N) return;
    const int lane = threadIdx.x & 63;
    const int g  = lane >> 4;
    const int sl = lane & 15;
    const int s = ptr[node];
    const int e = ptr[node + 1];

    float acc[4] = {};
    for (int i = s + g; i < e; i += 4) {
        const int src = col[i];
        uintx2 v = *(const uintx2*)(xw + (size_t)src * 32 + sl * 2);
        acc[0] += bf_lo(v.x); acc[1] += bf_hi(v.x);
        acc[2] += bf_lo(v.y); acc[3] += bf_hi(v.y);
    }
    #pragma unroll
    for (int j = 0; j < 4; ++j) {
        acc[j] += __shfl_xor(acc[j], 16, 64);
        acc[j] += __shfl_xor(acc[j], 32, 64);
    }
    float s1 = 0.f, s2 = 0.f;
    #pragma unroll
    for (int j = 0; j < 4; ++j) { s1 += acc[j]; s2 += acc[j] * acc[j]; }
    #pragma unroll
    for (int m = 8; m >= 1; m >>= 1) {
        s1 += __shfl_xor(s1, m, 64);
        s2 += __shfl_xor(s2, m, 64);
    }
    const float mean = s1 * (1.0f / 64.0f);
    const float var  = s2 * (1.0f / 64.0f) - mean * mean;
    const float inv  = rsqrtf(var + 1e-5f);

    if (g == 0) {
        float4 o;
        o.x = (acc[0] - mean) * inv;
        o.y = (acc[1] - mean) * inv;
        o.z = (acc[2] - mean) * inv;
        o.w = (acc[3] - mean) * inv;
        if (RELU) {
            o.x = fmaxf(o.x, 0.f); o.y = fmaxf(o.y, 0.f);
            o.z = fmaxf(o.z, 0.f); o.w = fmaxf(o.w, 0.f);
        }
        *(float4*)(out + (size_t)node * 64 + sl * 4) = o;
    }
}

extern "C" void kernel_launch(void* const* d_in, const int* in_sizes, int n_in,
                              void* d_out, int out_size, void* d_ws, size_t ws_size,
                              hipStream_t stream) {
    const float* feat = (const float*)d_in[0];   // [N,128]
    const float* W0   = (const float*)d_in[1];   // [128,128]
    const float* W1   = (const float*)d_in[2];   // [128,128]
    const float* W2   = (const float*)d_in[3];   // [128,64]
    const int*   ptr  = (const int*)d_in[4];     // [N+1]
    const int*   col  = (const int*)d_in[5];     // [E]
    // d_in[6] = edge_rows, unused (CSR ptr encodes the same segments)

    const int N = in_sizes[4] - 1;               // 50000

    unsigned int* xwp = (unsigned int*)d_ws;             // [N,64] uint (bf16x2)
    float*        hf  = (float*)(xwp + (size_t)N * 64);  // [N,128] fp32 h
    unsigned int* WtP = (unsigned int*)(hf + (size_t)N * 128);  // 3 x [128,64] uint
    float*        out = (float*)d_out;                   // [N,64]

    const int gemmBlocks = (N + 63) / 64;        // 782
    const int aggBlocks  = (N + 3) / 4;          // 12500

    cvt_w<<<48, 256, 0, stream>>>(W0, W1, W2, WtP);

    // Layer 0
    gemm_mfma<128><<<gemmBlocks, 256, 0, stream>>>(feat, WtP, xwp, N);
    agg_ln128<true><<<aggBlocks, 256, 0, stream>>>(xwp, ptr, col, hf, N);
    // Layer 1
    gemm_mfma<128><<<gemmBlocks, 256, 0, stream>>>(hf, WtP + 128 * 64, xwp, N);
    agg_ln128<true><<<aggBlocks, 256, 0, stream>>>(xwp, ptr, col, hf, N);
    // Layer 2 (D_out=64, no ReLU)
    gemm_mfma<64><<<gemmBlocks, 256, 0, stream>>>(hf, WtP + 2 * 128 * 64, xwp, N);
    agg_ln64<false><<<aggBlocks, 256, 0, stream>>>(xwp, ptr, col, out, N);
}